// Round 2
// baseline (226.416 us; speedup 1.0000x reference)
//
#include <hip/hip_runtime.h>

// YOLO loss forward on MI355X.
// input/target: (B=256, C=25, S=64, S=64) fp32, row-major.
// R2: split channels across 5 wave-uniform block groups to raise
// memory-level parallelism (each thread batches 10-11 independent float4
// loads) and oversubscribe the CUs (5120 blocks = 80 waves/CU of work).

#define COORD 5.0f
#define NOOBJ 0.5f

constexpr int B = 256;
constexpr int C = 25;
constexpr int S = 64;
constexpr int SS = S * S;                    // 4096 spatial positions per image
constexpr int CH_STRIDE4 = SS / 4;           // 1024 float4 per channel plane
constexpr int IMG_STRIDE4 = C * CH_STRIDE4;  // 25600 float4 per image
constexpr int NPOS4 = B * SS / 4;            // 262144 float4-groups
constexpr int BLOCKS_PER_GROUP = NPOS4 / 256; // 1024
constexpr int NGROUPS = 5;                   // 1 box group + 4 class groups

__global__ void zero_out_kernel(float* out) { out[0] = 0.0f; }

__global__ __launch_bounds__(256) void yolo_loss_kernel(
        const float4* __restrict__ in, const float4* __restrict__ tg,
        float* __restrict__ out) {
    // Interleave groups across consecutive blocks for L2/L3 reuse of the
    // t[4] mask plane.
    const int group = blockIdx.x % NGROUPS;          // 0..4, wave-uniform
    const int chunk = blockIdx.x / NGROUPS;          // 0..1023
    const int gpos = (chunk << 8) | threadIdx.x;     // 0..262143
    const int b = gpos >> 10;
    const int pp = gpos & 1023;
    const int base = b * IMG_STRIDE4 + pp;

    float acc = 0.0f;

    if (group == 0) {
        // Box + confidence: channels 0..4 of both tensors (10 independent loads).
        float4 p0 = in[base + 0 * CH_STRIDE4];
        float4 p1 = in[base + 1 * CH_STRIDE4];
        float4 p2 = in[base + 2 * CH_STRIDE4];
        float4 p3 = in[base + 3 * CH_STRIDE4];
        float4 p4 = in[base + 4 * CH_STRIDE4];
        float4 t0 = tg[base + 0 * CH_STRIDE4];
        float4 t1 = tg[base + 1 * CH_STRIDE4];
        float4 t2 = tg[base + 2 * CH_STRIDE4];
        float4 t3 = tg[base + 3 * CH_STRIDE4];
        float4 t4 = tg[base + 4 * CH_STRIDE4];

        const float invBlocks = 1.0f / (float)S;
        float px4[4] = {p0.x, p0.y, p0.z, p0.w};
        float py4[4] = {p1.x, p1.y, p1.z, p1.w};
        float pw4[4] = {p2.x, p2.y, p2.z, p2.w};
        float ph4[4] = {p3.x, p3.y, p3.z, p3.w};
        float pc4[4] = {p4.x, p4.y, p4.z, p4.w};
        float tx4[4] = {t0.x, t0.y, t0.z, t0.w};
        float ty4[4] = {t1.x, t1.y, t1.z, t1.w};
        float tw4[4] = {t2.x, t2.y, t2.z, t2.w};
        float th4[4] = {t3.x, t3.y, t3.z, t3.w};
        float tc4[4] = {t4.x, t4.y, t4.z, t4.w};

        #pragma unroll
        for (int k = 0; k < 4; ++k) {
            const float px = px4[k], py = py4[k], pw = pw4[k], ph = ph4[k];
            const float pc = pc4[k];
            const float tx = tx4[k], ty = ty4[k], tw = tw4[k], th = th4[k];
            const float m = (tc4[k] > 0.0f) ? 1.0f : 0.0f;

            // IoU (forward values only; stop_gradient irrelevant for fwd)
            const float c1x = px * invBlocks, c1y = py * invBlocks;
            const float c2x = tx * invBlocks, c2y = ty * invBlocks;
            const float x1a = c1x - pw * 0.5f, x2a = c1x + pw * 0.5f;
            const float y1a = c1y - ph * 0.5f, y2a = c1y + ph * 0.5f;
            const float x1b = c2x - tw * 0.5f, x2b = c2x + tw * 0.5f;
            const float y1b = c2y - th * 0.5f, y2b = c2y + th * 0.5f;
            const float dx = fminf(x2a, x2b) - fmaxf(x1a, x1b);
            const float dy = fminf(y2a, y2b) - fmaxf(y1a, y1b);
            const float inter = dx * dy;
            const float uni = pw * ph + tw * th - inter;
            const bool pos = (dx > 0.0f) && (dy > 0.0f);
            const float iou = pos ? (inter / uni) : 0.0f;

            const float ex = px - tx, ey = py - ty;
            acc += COORD * m * (ex * ex + ey * ey);
            const float sw = sqrtf(pw) - sqrtf(tw);
            const float sh = sqrtf(ph) - sqrtf(th);
            acc += COORD * m * (sw * sw + sh * sh);
            const float ec = pc - iou;
            acc += m * ec * ec;
            acc += NOOBJ * (1.0f - m) * (pc * pc);
        }
    } else {
        // Class group: 5 channels starting at 5 + (group-1)*5, plus t[4] mask.
        const int c0 = 5 + (group - 1) * 5;
        float4 t4 = tg[base + 4 * CH_STRIDE4];
        float4 pv[5], tv[5];
        #pragma unroll
        for (int j = 0; j < 5; ++j) {
            pv[j] = in[base + (c0 + j) * CH_STRIDE4];
            tv[j] = tg[base + (c0 + j) * CH_STRIDE4];
        }
        const float m0 = (t4.x > 0.0f) ? 1.0f : 0.0f;
        const float m1 = (t4.y > 0.0f) ? 1.0f : 0.0f;
        const float m2 = (t4.z > 0.0f) ? 1.0f : 0.0f;
        const float m3 = (t4.w > 0.0f) ? 1.0f : 0.0f;
        float a0 = 0.0f, a1 = 0.0f, a2 = 0.0f, a3 = 0.0f;
        #pragma unroll
        for (int j = 0; j < 5; ++j) {
            float d;
            d = pv[j].x - tv[j].x; a0 += d * d;
            d = pv[j].y - tv[j].y; a1 += d * d;
            d = pv[j].z - tv[j].z; a2 += d * d;
            d = pv[j].w - tv[j].w; a3 += d * d;
        }
        acc = m0 * a0 + m1 * a1 + m2 * a2 + m3 * a3;
    }

    // wave64 reduce
    #pragma unroll
    for (int off = 32; off > 0; off >>= 1)
        acc += __shfl_down(acc, off, 64);

    __shared__ float smem[4];
    const int lane = threadIdx.x & 63;
    const int wid = threadIdx.x >> 6;
    if (lane == 0) smem[wid] = acc;
    __syncthreads();
    if (threadIdx.x == 0) {
        const float s = smem[0] + smem[1] + smem[2] + smem[3];
        atomicAdd(out, s);
    }
}

extern "C" void kernel_launch(void* const* d_in, const int* in_sizes, int n_in,
                              void* d_out, int out_size, void* d_ws, size_t ws_size,
                              hipStream_t stream) {
    const float4* in = (const float4*)d_in[0];
    const float4* tg = (const float4*)d_in[1];
    float* out = (float*)d_out;

    // d_out is re-poisoned to 0xAA before every timed launch -> zero it first.
    zero_out_kernel<<<1, 1, 0, stream>>>(out);

    const int threads = 256;
    const int blocks = BLOCKS_PER_GROUP * NGROUPS;  // 5120
    yolo_loss_kernel<<<blocks, threads, 0, stream>>>(in, tg, out);
}

// Round 3
// 225.796 us; speedup vs baseline: 1.0027x; 1.0027x over previous
//
#include <hip/hip_runtime.h>

// YOLO loss forward on MI355X.
// input/target: (B=256, C=25, S=64, S=64) fp32, row-major.
// R3: R2 was latency-bound with ~1 outstanding load/wave (VGPR_Count=32
// proved the compiler sank the load batch). Fix: issue all loads into
// named registers, then __builtin_amdgcn_sched_barrier(0) so the scheduler
// cannot interleave/sink them. launch_bounds(256,4) gives the RA room
// (<=128 VGPR). Expect ~10KB in flight per wave -> BW-bound.

#define COORD 5.0f
#define NOOBJ 0.5f

constexpr int B = 256;
constexpr int S = 64;
constexpr int SS = S * S;                     // 4096
constexpr int CH_STRIDE4 = SS / 4;            // 1024 float4 per channel plane
constexpr int IMG_STRIDE4 = 25 * CH_STRIDE4;  // 25600 float4 per image
constexpr int NPOS4 = B * SS / 4;             // 262144 float4-groups
constexpr int BLOCKS_PER_GROUP = NPOS4 / 256; // 1024
constexpr int NGROUPS = 5;                    // 1 box group + 4 class groups

__global__ void zero_out_kernel(float* out) { out[0] = 0.0f; }

__global__ __launch_bounds__(256, 4) void yolo_loss_kernel(
        const float4* __restrict__ in, const float4* __restrict__ tg,
        float* __restrict__ out) {
    const int group = blockIdx.x % NGROUPS;          // wave-uniform
    const int chunk = blockIdx.x / NGROUPS;          // 0..1023
    const int gpos = (chunk << 8) | threadIdx.x;     // 0..262143
    const int b = gpos >> 10;
    const int pp = gpos & 1023;
    const int base = b * IMG_STRIDE4 + pp;

    float acc = 0.0f;

    if (group == 0) {
        // ---- load phase: 10 independent float4 loads ----
        float4 p0 = in[base + 0 * CH_STRIDE4];
        float4 p1 = in[base + 1 * CH_STRIDE4];
        float4 p2 = in[base + 2 * CH_STRIDE4];
        float4 p3 = in[base + 3 * CH_STRIDE4];
        float4 p4 = in[base + 4 * CH_STRIDE4];
        float4 t0 = tg[base + 0 * CH_STRIDE4];
        float4 t1 = tg[base + 1 * CH_STRIDE4];
        float4 t2 = tg[base + 2 * CH_STRIDE4];
        float4 t3 = tg[base + 3 * CH_STRIDE4];
        float4 t4 = tg[base + 4 * CH_STRIDE4];
        __builtin_amdgcn_sched_barrier(0);   // do NOT sink loads below here
        // ---- compute phase ----
        const float invBlocks = 1.0f / (float)S;
        float px4[4] = {p0.x, p0.y, p0.z, p0.w};
        float py4[4] = {p1.x, p1.y, p1.z, p1.w};
        float pw4[4] = {p2.x, p2.y, p2.z, p2.w};
        float ph4[4] = {p3.x, p3.y, p3.z, p3.w};
        float pc4[4] = {p4.x, p4.y, p4.z, p4.w};
        float tx4[4] = {t0.x, t0.y, t0.z, t0.w};
        float ty4[4] = {t1.x, t1.y, t1.z, t1.w};
        float tw4[4] = {t2.x, t2.y, t2.z, t2.w};
        float th4[4] = {t3.x, t3.y, t3.z, t3.w};
        float tc4[4] = {t4.x, t4.y, t4.z, t4.w};

        #pragma unroll
        for (int k = 0; k < 4; ++k) {
            const float px = px4[k], py = py4[k], pw = pw4[k], ph = ph4[k];
            const float pc = pc4[k];
            const float tx = tx4[k], ty = ty4[k], tw = tw4[k], th = th4[k];
            const float m = (tc4[k] > 0.0f) ? 1.0f : 0.0f;

            const float c1x = px * invBlocks, c1y = py * invBlocks;
            const float c2x = tx * invBlocks, c2y = ty * invBlocks;
            const float x1a = c1x - pw * 0.5f, x2a = c1x + pw * 0.5f;
            const float y1a = c1y - ph * 0.5f, y2a = c1y + ph * 0.5f;
            const float x1b = c2x - tw * 0.5f, x2b = c2x + tw * 0.5f;
            const float y1b = c2y - th * 0.5f, y2b = c2y + th * 0.5f;
            const float dx = fminf(x2a, x2b) - fmaxf(x1a, x1b);
            const float dy = fminf(y2a, y2b) - fmaxf(y1a, y1b);
            const float inter = dx * dy;
            const float uni = pw * ph + tw * th - inter;
            const bool pos = (dx > 0.0f) && (dy > 0.0f);
            const float iou = pos ? (inter / uni) : 0.0f;

            const float ex = px - tx, ey = py - ty;
            acc += COORD * m * (ex * ex + ey * ey);
            const float sw = sqrtf(pw) - sqrtf(tw);
            const float sh = sqrtf(ph) - sqrtf(th);
            acc += COORD * m * (sw * sw + sh * sh);
            const float ec = pc - iou;
            acc += m * ec * ec;
            acc += NOOBJ * (1.0f - m) * (pc * pc);
        }
    } else {
        // ---- load phase: mask plane + 5 channels x 2 tensors = 11 loads ----
        const int c0 = 5 + (group - 1) * 5;
        float4 t4 = tg[base + 4 * CH_STRIDE4];
        float4 pv0 = in[base + (c0 + 0) * CH_STRIDE4];
        float4 pv1 = in[base + (c0 + 1) * CH_STRIDE4];
        float4 pv2 = in[base + (c0 + 2) * CH_STRIDE4];
        float4 pv3 = in[base + (c0 + 3) * CH_STRIDE4];
        float4 pv4 = in[base + (c0 + 4) * CH_STRIDE4];
        float4 tv0 = tg[base + (c0 + 0) * CH_STRIDE4];
        float4 tv1 = tg[base + (c0 + 1) * CH_STRIDE4];
        float4 tv2 = tg[base + (c0 + 2) * CH_STRIDE4];
        float4 tv3 = tg[base + (c0 + 3) * CH_STRIDE4];
        float4 tv4 = tg[base + (c0 + 4) * CH_STRIDE4];
        __builtin_amdgcn_sched_barrier(0);   // do NOT sink loads below here
        // ---- compute phase ----
        const float m0 = (t4.x > 0.0f) ? 1.0f : 0.0f;
        const float m1 = (t4.y > 0.0f) ? 1.0f : 0.0f;
        const float m2 = (t4.z > 0.0f) ? 1.0f : 0.0f;
        const float m3 = (t4.w > 0.0f) ? 1.0f : 0.0f;
        float a0 = 0.0f, a1 = 0.0f, a2 = 0.0f, a3 = 0.0f;
        float d;
        d = pv0.x - tv0.x; a0 += d * d;
        d = pv0.y - tv0.y; a1 += d * d;
        d = pv0.z - tv0.z; a2 += d * d;
        d = pv0.w - tv0.w; a3 += d * d;
        d = pv1.x - tv1.x; a0 += d * d;
        d = pv1.y - tv1.y; a1 += d * d;
        d = pv1.z - tv1.z; a2 += d * d;
        d = pv1.w - tv1.w; a3 += d * d;
        d = pv2.x - tv2.x; a0 += d * d;
        d = pv2.y - tv2.y; a1 += d * d;
        d = pv2.z - tv2.z; a2 += d * d;
        d = pv2.w - tv2.w; a3 += d * d;
        d = pv3.x - tv3.x; a0 += d * d;
        d = pv3.y - tv3.y; a1 += d * d;
        d = pv3.z - tv3.z; a2 += d * d;
        d = pv3.w - tv3.w; a3 += d * d;
        d = pv4.x - tv4.x; a0 += d * d;
        d = pv4.y - tv4.y; a1 += d * d;
        d = pv4.z - tv4.z; a2 += d * d;
        d = pv4.w - tv4.w; a3 += d * d;
        acc = m0 * a0 + m1 * a1 + m2 * a2 + m3 * a3;
    }

    // wave64 reduce
    #pragma unroll
    for (int off = 32; off > 0; off >>= 1)
        acc += __shfl_down(acc, off, 64);

    __shared__ float smem[4];
    const int lane = threadIdx.x & 63;
    const int wid = threadIdx.x >> 6;
    if (lane == 0) smem[wid] = acc;
    __syncthreads();
    if (threadIdx.x == 0) {
        const float s = smem[0] + smem[1] + smem[2] + smem[3];
        atomicAdd(out, s);
    }
}

extern "C" void kernel_launch(void* const* d_in, const int* in_sizes, int n_in,
                              void* d_out, int out_size, void* d_ws, size_t ws_size,
                              hipStream_t stream) {
    const float4* in = (const float4*)d_in[0];
    const float4* tg = (const float4*)d_in[1];
    float* out = (float*)d_out;

    // d_out is re-poisoned to 0xAA before every timed launch -> zero it first.
    zero_out_kernel<<<1, 1, 0, stream>>>(out);

    const int threads = 256;
    const int blocks = BLOCKS_PER_GROUP * NGROUPS;  // 5120
    yolo_loss_kernel<<<blocks, threads, 0, stream>>>(in, tg, out);
}